// Round 3
// baseline (328.411 us; speedup 1.0000x reference)
//
#include <hip/hip_runtime.h>
#include <hip/hip_bf16.h>
#include <hip/hip_cooperative_groups.h>

namespace cg = cooperative_groups;

// Problem constants
// B=64, C=4, H=256, W=256; SCALES=(8,16,32); windows=(0,250,500,750,1000)
// KEY_INT = 0x5D1CE5 = 6102245
// base_core = (KEY_INT * 2654435761) % 10007  (product ~1.62e19 fits in u64)
static constexpr unsigned long long KEY_MUL =
    (6102245ULL * 2654435761ULL) % 10007ULL;
static constexpr int HASH_MOD = 10007;

// ---------------------------------------------------------------------------
// Single cooperative kernel, 1024 blocks x 256 threads, 4 blocks/CU pinned.
//
// Phase 1 (pool): block b = (ch = b&31 plane-chunk, pr = b>>5 patch-row).
//   Sums 8 planes x 8 rows x 256 cols -> 32 partial patch sums ->
//   ws_partial[(pr*32+pc)*32 + ch].  Reads latent (64 MiB) once.
//
// grid.sync() (+ device fences for cross-XCD visibility of partials)
//
// Phase 2 (bias+add): block b = (plane = b>>2, q = b&3 -> rows [q*64,q*64+64)).
//   Each thread reduces one patch's 32 chunk-partials (contiguous 128 B) ->
//   s8[256] in LDS; computes combined bias btot[8][32] = g8+g16+g32 for the
//   slab (redundant per block, ~336 cosf); then streams noise+bias -> out
//   with 4-deep float4 ILP.  Reads noise (64 MiB), writes out (64 MiB).
// ---------------------------------------------------------------------------
__global__ __launch_bounds__(256, 4) void fused_kernel(
    const float* __restrict__ noise, const float* __restrict__ latent,
    const int* __restrict__ tstep, float* __restrict__ out,
    float* __restrict__ ws_partial) {
  const int t = threadIdx.x;
  const int b = blockIdx.x;

  __shared__ float red[4][32];
  __shared__ float s8[256];
  __shared__ float btot[256];

  // ---------------- Phase 1: pool latent ----------------
  {
    const int ch = b & 31;  // plane chunk (8 planes)
    const int pr = b >> 5;  // patch row 0..31
    const int cl = t & 63;  // float4 column 0..63
    const int rg = t >> 6;  // row group 0..3
    float acc = 0.0f;
    const float4* base = reinterpret_cast<const float4*>(latent);
#pragma unroll
    for (int pl = 0; pl < 8; ++pl) {
      const float4* prow = base + (size_t)(ch * 8 + pl) * 16384;
#pragma unroll
      for (int rr = 0; rr < 2; ++rr) {
        float4 v = prow[(pr * 8 + rg + rr * 4) * 64 + cl];
        acc += (v.x + v.y) + (v.z + v.w);
      }
    }
    acc += __shfl_xor(acc, 1, 64);  // lanes 2c,2c+1 share an 8-wide patch col
    if ((cl & 1) == 0) red[rg][cl >> 1] = acc;
    __syncthreads();
    if (t < 32) {
      float s = (red[0][t] + red[1][t]) + (red[2][t] + red[3][t]);
      ws_partial[(pr * 32 + t) * 32 + (b & 31)] = s;
    }
  }

  __threadfence();          // release partials device-wide (cross-XCD)
  cg::this_grid().sync();
  __threadfence();          // acquire side

  // ---------------- Phase 2: bias table + add ----------------
  const int q = b & 3;           // row slab [q*64, q*64+64) of plane b>>2
  const int lr = t >> 5;         // local patch-8 row 0..7
  const int lc = t & 31;         // patch-8 col 0..31

  // reduce this thread's patch: 32 contiguous chunk-partials
  {
    const int patch = (8 * q + lr) * 32 + lc;
    const float4* p4 = reinterpret_cast<const float4*>(ws_partial) + patch * 8;
    float s = 0.0f;
#pragma unroll
    for (int c = 0; c < 8; ++c) {
      float4 v = p4[c];
      s += (v.x + v.y) + (v.z + v.w);
    }
    s8[t] = s;
  }
  __syncthreads();

  {
    const int ts = *tstep;
    // bucket = searchsorted(windows,'right') - 1 = count(w <= ts) - 1
    int bucket = -1;
    const int wins[5] = {0, 250, 500, 750, 1000};
#pragma unroll
    for (int k = 0; k < 5; ++k) bucket += (ts >= wins[k]) ? 1 : 0;

    const double expo = exp(-(double)ts / 1000.0);
    const float phase_k = (float)(6.2831853 / 10007.0);

    float bias = 0.0f;
    // ---- scale 8 ----
    {
      const int p = 8, i = 8 * q + lr, j = lc;
      const long long bb =
          ((long long)KEY_MUL + p * 97 + bucket * 139 + 10 * HASH_MOD) % HASH_MOD;
      const int h = (int)((bb + (long long)i * (p * 131) + (long long)j * (p * 137)) % HASH_MOD);
      const float pooled = s8[t] * (1.0f / 16384.0f);  // /(B*C*64)
      const float strength = (float)(0.05 / sqrt(8.0) * expo);
      bias += cosf(pooled * 3.0f + (float)h * phase_k) * strength;
    }
    // ---- scale 16 (2x2 aggregate, redundant per thread) ----
    {
      const int p = 16, i = 4 * q + (lr >> 1), j = lc >> 1;
      const long long bb =
          ((long long)KEY_MUL + p * 97 + bucket * 139 + 10 * HASH_MOD) % HASH_MOD;
      const int h = (int)((bb + (long long)i * (p * 131) + (long long)j * (p * 137)) % HASH_MOD);
      const int r0 = (lr & ~1) * 32, c0 = lc & ~1;
      const float s = (s8[r0 + c0] + s8[r0 + c0 + 1]) +
                      (s8[r0 + 32 + c0] + s8[r0 + 32 + c0 + 1]);
      const float pooled = s * (1.0f / 65536.0f);  // /(B*C*256)
      const float strength = (float)(0.05 / sqrt(16.0) * expo);
      bias += cosf(pooled * 3.0f + (float)h * phase_k) * strength;
    }
    // ---- scale 32 (4x4 aggregate, redundant per thread) ----
    {
      const int p = 32, i = 2 * q + (lr >> 2), j = lc >> 2;
      const long long bb =
          ((long long)KEY_MUL + p * 97 + bucket * 139 + 10 * HASH_MOD) % HASH_MOD;
      const int h = (int)((bb + (long long)i * (p * 131) + (long long)j * (p * 137)) % HASH_MOD);
      const int r0 = (lr & ~3) * 32, c0 = lc & ~3;
      float s = 0.0f;
#pragma unroll
      for (int di = 0; di < 4; ++di)
#pragma unroll
        for (int dj = 0; dj < 4; ++dj) s += s8[r0 + di * 32 + c0 + dj];
      const float pooled = s * (1.0f / 262144.0f);  // /(B*C*1024)
      const float strength = (float)(0.05 / sqrt(32.0) * expo);
      bias += cosf(pooled * 3.0f + (float)h * phase_k) * strength;
    }
    btot[t] = bias;
  }
  __syncthreads();

  // ---- stream: out = noise + btot, 4096 float4 per slab, 16/thread ----
  {
    const size_t slab = (size_t)(b >> 2) * 16384 + (size_t)q * 4096;
    const float4* __restrict__ n4 = reinterpret_cast<const float4*>(noise) + slab;
    float4* __restrict__ o4 = reinterpret_cast<float4*>(out) + slab;
    const int c8 = (t & 63) >> 1;   // btot col
    const int r0 = t >> 6;          // row offset within 4-row step
#pragma unroll
    for (int kk = 0; kk < 4; ++kk) {
      float4 v[4];
      float bs[4];
#pragma unroll
      for (int k2 = 0; k2 < 4; ++k2) {
        const int k = kk * 4 + k2;
        v[k2] = n4[k * 256 + t];
        const int lrow = k * 4 + r0;  // local row 0..63
        bs[k2] = btot[(lrow >> 3) * 32 + c8];
      }
#pragma unroll
      for (int k2 = 0; k2 < 4; ++k2) {
        const int k = kk * 4 + k2;
        float4 w = v[k2];
        w.x += bs[k2]; w.y += bs[k2]; w.z += bs[k2]; w.w += bs[k2];
        o4[k * 256 + t] = w;
      }
    }
  }
}

extern "C" void kernel_launch(void* const* d_in, const int* in_sizes, int n_in,
                              void* d_out, int out_size, void* d_ws, size_t ws_size,
                              hipStream_t stream) {
  const float* noise  = (const float*)d_in[0];
  const float* latent = (const float*)d_in[1];
  const int*   tstep  = (const int*)d_in[2];
  float* out = (float*)d_out;
  float* ws  = (float*)d_ws;  // needs 32 KiB for partials

  void* args[] = {(void*)&noise, (void*)&latent, (void*)&tstep,
                  (void*)&out,   (void*)&ws};
  hipLaunchCooperativeKernel((void*)fused_kernel, dim3(1024), dim3(256),
                             args, 0, stream);
}

// Round 4
// 38.139 us; speedup vs baseline: 8.6110x; 8.6110x over previous
//
#include <hip/hip_runtime.h>
#include <hip/hip_bf16.h>

// Problem constants
// B=64, C=4, H=256, W=256; SCALES=(8,16,32); windows=(0,250,500,750,1000)
// KEY_INT = 0x5D1CE5 = 6102245
// base_core = (KEY_INT * 2654435761) % 10007  (product ~1.62e19 fits in u64)
static constexpr unsigned long long KEY_MUL =
    (6102245ULL * 2654435761ULL) % 10007ULL;
static constexpr int HASH_MOD = 10007;

// ---------------------------------------------------------------------------
// Kernel 1: pool latent -> per-chunk partial sums of 8x8 patches.
// grid = (NCH plane-chunks, 32 patch-rows), block = 256.
// Block (ch, pr): sums planes [ch*PPC,(ch+1)*PPC) over patch-row pr ->
// 32 partials -> ws_partial[(pr*32+pc)*NCH + ch].
// ---------------------------------------------------------------------------
template <int NCH>
__global__ __launch_bounds__(256) void pool_kernel(
    const float* __restrict__ latent, float* __restrict__ ws_partial) {
  constexpr int PPC = 256 / NCH;  // planes per chunk
  const int pr = blockIdx.y;
  const int ch = blockIdx.x;
  const int t  = threadIdx.x;
  const int cl = t & 63;   // float4 column (0..63)
  const int rg = t >> 6;   // row group 0..3

  float acc = 0.0f;
  const float4* base = reinterpret_cast<const float4*>(latent);
#pragma unroll 8
  for (int pl = 0; pl < PPC; ++pl) {
    const float4* prow = base + (size_t)(ch * PPC + pl) * 16384;
#pragma unroll
    for (int rr = 0; rr < 2; ++rr) {
      float4 v = prow[(pr * 8 + rg + rr * 4) * 64 + cl];
      acc += (v.x + v.y) + (v.z + v.w);
    }
  }
  acc += __shfl_xor(acc, 1, 64);  // lanes 2c,2c+1 share an 8-wide patch col

  __shared__ float lds[4][32];
  if ((cl & 1) == 0) lds[rg][cl >> 1] = acc;
  __syncthreads();
  if (t < 32) {
    float s = (lds[0][t] + lds[1][t]) + (lds[2][t] + lds[3][t]);
    ws_partial[(pr * 32 + t) * NCH + ch] = s;
  }
}

// ---------------------------------------------------------------------------
// Kernel 2: bias build + stream add, 1024 blocks x 256 threads.
// Block b: plane = b>>2, row slab q = b&3 -> rows [q*64, q*64+64).
// Thread t = (lr = t>>5 in 0..7, lc = t&31): reduces patch (8q+lr, lc)'s
// NCH chunk-partials -> s8 in LDS; computes combined bias (g8+g16+g32,
// redundant per block, 3 cosf/thread); streams 16 float4 of noise+bias->out.
// Partials (<=128 KiB) are L2/L3-resident broadcast reads.
// ---------------------------------------------------------------------------
template <int NCH>
__global__ __launch_bounds__(256, 4) void bias_add_kernel(
    const float* __restrict__ noise, const float* __restrict__ ws_partial,
    const int* __restrict__ tstep, float* __restrict__ out) {
  const int t = threadIdx.x;
  const int b = blockIdx.x;
  const int q = b & 3;
  const int lr = t >> 5;  // local patch-8 row 0..7
  const int lc = t & 31;  // patch-8 col 0..31

  __shared__ float s8[256];
  __shared__ float btot[256];

  const int ts = *tstep;  // issue early

  // reduce this thread's patch: NCH contiguous chunk-partials
  {
    const int patch = (8 * q + lr) * 32 + lc;
    float s = 0.0f;
    if constexpr (NCH >= 4) {
      const float4* p4 =
          reinterpret_cast<const float4*>(ws_partial) + patch * (NCH / 4);
#pragma unroll
      for (int c = 0; c < NCH / 4; ++c) {
        float4 v = p4[c];
        s += (v.x + v.y) + (v.z + v.w);
      }
    } else {
#pragma unroll
      for (int c = 0; c < NCH; ++c) s += ws_partial[patch * NCH + c];
    }
    s8[t] = s;
  }
  __syncthreads();

  {
    // bucket = searchsorted(windows,'right') - 1 = count(w <= ts) - 1
    int bucket = -1;
    const int wins[5] = {0, 250, 500, 750, 1000};
#pragma unroll
    for (int k = 0; k < 5; ++k) bucket += (ts >= wins[k]) ? 1 : 0;

    const double expo = exp(-(double)ts / 1000.0);
    const float phase_k = (float)(6.2831853 / 10007.0);

    float bias = 0.0f;
    // ---- scale 8 ----
    {
      const int p = 8, i = 8 * q + lr, j = lc;
      const long long bb =
          ((long long)KEY_MUL + p * 97 + bucket * 139 + 10 * HASH_MOD) % HASH_MOD;
      const int h = (int)((bb + (long long)i * (p * 131) + (long long)j * (p * 137)) % HASH_MOD);
      const float pooled = s8[t] * (1.0f / 16384.0f);  // /(B*C*64)
      const float strength = (float)(0.05 / sqrt(8.0) * expo);
      bias += cosf(pooled * 3.0f + (float)h * phase_k) * strength;
    }
    // ---- scale 16 (2x2 aggregate of s8, redundant per thread) ----
    {
      const int p = 16, i = 4 * q + (lr >> 1), j = lc >> 1;
      const long long bb =
          ((long long)KEY_MUL + p * 97 + bucket * 139 + 10 * HASH_MOD) % HASH_MOD;
      const int h = (int)((bb + (long long)i * (p * 131) + (long long)j * (p * 137)) % HASH_MOD);
      const int r0 = (lr & ~1) * 32, c0 = lc & ~1;
      const float s = (s8[r0 + c0] + s8[r0 + c0 + 1]) +
                      (s8[r0 + 32 + c0] + s8[r0 + 32 + c0 + 1]);
      const float pooled = s * (1.0f / 65536.0f);  // /(B*C*256)
      const float strength = (float)(0.05 / sqrt(16.0) * expo);
      bias += cosf(pooled * 3.0f + (float)h * phase_k) * strength;
    }
    // ---- scale 32 (4x4 aggregate of s8, redundant per thread) ----
    {
      const int p = 32, i = 2 * q + (lr >> 2), j = lc >> 2;
      const long long bb =
          ((long long)KEY_MUL + p * 97 + bucket * 139 + 10 * HASH_MOD) % HASH_MOD;
      const int h = (int)((bb + (long long)i * (p * 131) + (long long)j * (p * 137)) % HASH_MOD);
      const int r0 = (lr & ~3) * 32, c0 = lc & ~3;
      float s = 0.0f;
#pragma unroll
      for (int di = 0; di < 4; ++di)
#pragma unroll
        for (int dj = 0; dj < 4; ++dj) s += s8[r0 + di * 32 + c0 + dj];
      const float pooled = s * (1.0f / 262144.0f);  // /(B*C*1024)
      const float strength = (float)(0.05 / sqrt(32.0) * expo);
      bias += cosf(pooled * 3.0f + (float)h * phase_k) * strength;
    }
    btot[t] = bias;
  }
  __syncthreads();

  // ---- stream: out = noise + btot; 4096 float4 per slab, 16/thread ----
  {
    const size_t slab = (size_t)(b >> 2) * 16384 + (size_t)q * 4096;
    const float4* __restrict__ n4 = reinterpret_cast<const float4*>(noise) + slab;
    float4* __restrict__ o4 = reinterpret_cast<float4*>(out) + slab;
    const int c8 = (t & 63) >> 1;  // btot col
    const int r0 = t >> 6;         // row offset within a 4-row step
#pragma unroll
    for (int kk = 0; kk < 4; ++kk) {
      float4 v[4];
      float bs[4];
#pragma unroll
      for (int k2 = 0; k2 < 4; ++k2) {
        const int k = kk * 4 + k2;
        v[k2] = n4[k * 256 + t];
        const int lrow = k * 4 + r0;  // local row 0..63
        bs[k2] = btot[(lrow >> 3) * 32 + c8];
      }
#pragma unroll
      for (int k2 = 0; k2 < 4; ++k2) {
        const int k = kk * 4 + k2;
        float4 w = v[k2];
        w.x += bs[k2]; w.y += bs[k2]; w.z += bs[k2]; w.w += bs[k2];
        o4[k * 256 + t] = w;
      }
    }
  }
}

extern "C" void kernel_launch(void* const* d_in, const int* in_sizes, int n_in,
                              void* d_out, int out_size, void* d_ws, size_t ws_size,
                              hipStream_t stream) {
  const float* noise  = (const float*)d_in[0];
  const float* latent = (const float*)d_in[1];
  const int*   tstep  = (const int*)d_in[2];
  float* out = (float*)d_out;
  float* ws  = (float*)d_ws;

  const size_t need32 = (size_t)(1024 * 32) * sizeof(float);  // 128 KiB
  const size_t need8  = (size_t)(1024 * 8) * sizeof(float);   // 32 KiB

  if (ws_size >= need32) {
    pool_kernel<32><<<dim3(32, 32), 256, 0, stream>>>(latent, ws);
    bias_add_kernel<32><<<1024, 256, 0, stream>>>(noise, ws, tstep, out);
  } else if (ws_size >= need8) {
    pool_kernel<8><<<dim3(8, 32), 256, 0, stream>>>(latent, ws);
    bias_add_kernel<8><<<1024, 256, 0, stream>>>(noise, ws, tstep, out);
  } else {
    pool_kernel<1><<<dim3(1, 32), 256, 0, stream>>>(latent, ws);
    bias_add_kernel<1><<<1024, 256, 0, stream>>>(noise, ws, tstep, out);
  }
}